// Round 11
// baseline (332.264 us; speedup 1.0000x reference)
//
#include <hip/hip_runtime.h>
#include <hip/hip_bf16.h>

#define BATCH 2
#define SEQ   2048
#define DIM   2048
#define NHEAD 16
#define HDIM  128

// LDS strides (elements) for attn V/P tiles. Multiples of 8 (16B alignment).
#define VSTRIDE 72
#define PSTRIDE 72

typedef __bf16 bf16;
typedef __attribute__((ext_vector_type(2))) __bf16 bf16x2;
typedef __attribute__((ext_vector_type(4))) __bf16 bf16x4;
typedef __attribute__((ext_vector_type(8))) __bf16 bf16x8;
typedef __attribute__((ext_vector_type(4))) float f32x4;

__device__ __forceinline__ void load_lds16(const bf16* g, bf16* l) {
    __builtin_amdgcn_global_load_lds((const __attribute__((address_space(1))) void*)g,
                                     (__attribute__((address_space(3))) void*)l, 16, 0, 0);
}

// v_exp_f32: D = 2^S0 (hardware transcendental)
__device__ __forceinline__ float exp2_hw(float x) { return __builtin_amdgcn_exp2f(x); }

// ---------------------------------------------------------------------------
// Fused prep (single dispatch, tasks run concurrently):
//   blocks [0, 4096):        cvt x fp32 -> xb bf16 (8 elems/thread)
//   blocks [4096, 5120):     transpose Wq -> Wtq (64x64 tiles)
//   blocks [5120, 6144):     transpose Wo -> Wto
// ---------------------------------------------------------------------------
__global__ __launch_bounds__(256)
void prep_kernel(const float* __restrict__ x, bf16* __restrict__ xb,
                 const float* __restrict__ Wq, bf16* __restrict__ Wtq,
                 const float* __restrict__ Wo, bf16* __restrict__ Wto)
{
    __shared__ bf16 T[64 * 72];
    const int bid = blockIdx.x;
    if (bid < 4096) {
        const size_t i = ((size_t)bid * 256 + threadIdx.x) * 8;
        const float4 f0 = *(const float4*)(x + i);
        const float4 f1 = *(const float4*)(x + i + 4);
        *(bf16x8*)(xb + i) = (bf16x8){(bf16)f0.x, (bf16)f0.y, (bf16)f0.z, (bf16)f0.w,
                                      (bf16)f1.x, (bf16)f1.y, (bf16)f1.z, (bf16)f1.w};
        return;
    }
    int t = bid - 4096;
    const float* W  = (t < 1024) ? Wq : Wo;
    bf16*        Wt = (t < 1024) ? Wtq : Wto;
    t &= 1023;
    const int kb = (t >> 5) * 64, nb = (t & 31) * 64;

    const int a = threadIdx.x & 31;     // k-pair index
    const int g = threadIdx.x >> 5;     // n-slice 0..7
    {
        const float* s0 = W + (size_t)(kb + 2 * a) * DIM + nb + g * 8;
        const float4 r0a = *(const float4*)(s0);
        const float4 r0b = *(const float4*)(s0 + 4);
        const float4 r1a = *(const float4*)(s0 + DIM);
        const float4 r1b = *(const float4*)(s0 + DIM + 4);
        float v0[8] = {r0a.x, r0a.y, r0a.z, r0a.w, r0b.x, r0b.y, r0b.z, r0b.w};
        float v1[8] = {r1a.x, r1a.y, r1a.z, r1a.w, r1b.x, r1b.y, r1b.z, r1b.w};
        #pragma unroll
        for (int i = 0; i < 8; ++i)
            *(bf16x2*)&T[(g * 8 + i) * 72 + 2 * a] = (bf16x2){(bf16)v0[i], (bf16)v1[i]};
    }
    __syncthreads();

    const int r  = threadIdx.x >> 2;          // output n row 0..63
    const int k0 = (threadIdx.x & 3) * 16;    // k chunk
    bf16x8 o0 = *(const bf16x8*)&T[r * 72 + k0];
    bf16x8 o1 = *(const bf16x8*)&T[r * 72 + k0 + 8];
    *(bf16x8*)(Wt + (size_t)(nb + r) * DIM + kb + k0)     = o0;
    *(bf16x8*)(Wt + (size_t)(nb + r) * DIM + kb + k0 + 8) = o1;
}

// ---------------------------------------------------------------------------
// GEMM — REVERTED to round-3 gemm_bt8 verbatim (best measured; round-10's
// 256x256/128-block variant regressed 73->96 us/gemm: GEMM is per-CU
// rate-bound, not chip-BW-bound).
//   C[M,N] = A[M,K] @ Bt[N,K]^T, bf16 in. BM=128, BN=256, 8 waves 2Mx4N,
//   K in 64 slices of 32, 4-slot LDS ring (96 KiB), 256 blocks = 256 CUs.
// ---------------------------------------------------------------------------
#define GEMM_PHASE(S, VM, DO_STAGE)                                            \
    {                                                                          \
        const bf16* Aq = Ls + ((S) & 3) * 12288;                               \
        const bf16* Bq = Aq + 4096;                                            \
        bf16x8 a[4], b[4];                                                     \
        _Pragma("unroll")                                                      \
        for (int i = 0; i < 4; ++i) a[i] = *(const bf16x8*)(Aq + offA[i]);     \
        _Pragma("unroll")                                                      \
        for (int j = 0; j < 4; ++j) b[j] = *(const bf16x8*)(Bq + offB[j]);     \
        if (DO_STAGE) {                                                        \
            bf16* lb = Ls + (((S) + 3) & 3) * 12288 + wave * 512;              \
            const int ko = ((S) + 3) * 32;                                     \
            load_lds16(gA + ko, lb);                                           \
            load_lds16(gB0 + ko, lb + 4096);                                   \
            load_lds16(gB1 + ko, lb + 8192);                                   \
        }                                                                      \
        __builtin_amdgcn_s_barrier();                                          \
        __builtin_amdgcn_s_setprio(1);                                         \
        _Pragma("unroll")                                                      \
        for (int i = 0; i < 4; ++i) {                                          \
            _Pragma("unroll")                                                  \
            for (int j = 0; j < 4; ++j)                                        \
                acc[i][j] = __builtin_amdgcn_mfma_f32_16x16x32_bf16(a[i], b[j], acc[i][j], 0, 0, 0); \
        }                                                                      \
        __builtin_amdgcn_s_setprio(0);                                         \
        if ((VM) == 6)      asm volatile("s_waitcnt vmcnt(6)" ::: "memory");   \
        else if ((VM) == 3) asm volatile("s_waitcnt vmcnt(3)" ::: "memory");   \
        else if ((VM) == 0) asm volatile("s_waitcnt vmcnt(0)" ::: "memory");   \
        if ((VM) >= 0) {                                                       \
            __builtin_amdgcn_s_barrier();                                      \
            asm volatile("" ::: "memory");                                     \
        }                                                                      \
    }

template<bool OUT_F32_BIAS>
__global__ __launch_bounds__(512, 2)
void gemm_bt8(const bf16* __restrict__ A, const bf16* __restrict__ Bt,
              const float* __restrict__ bias, void* __restrict__ Cptr,
              int M, int N, int K)
{
    __shared__ bf16 Ls[4 * 12288];   // 96 KiB ring: slot = A[128][32] + B[256][32]

    const int tid  = threadIdx.x;
    const int wave = tid >> 6;        // 0..7
    const int lane = tid & 63;
    const int quad = lane >> 4;
    const int l16  = lane & 15;
    const int wr   = wave >> 2;       // 0..1: 64-row block
    const int wc   = wave & 3;        // 0..3: 64-col block

    // XCD swizzle (bijective: 256 blocks, 256%8==0).
    const int cpx = gridDim.x >> 3;
    const int logical = (blockIdx.x & 7) * cpx + (blockIdx.x >> 3);
    const int rowBase = (logical >> 3) * 128;   // NT = N/256 = 8
    const int colBase = (logical & 7) * 256;

    // s-invariant swizzled ds_read element offsets (region-relative)
    int offA[4], offB[4];
    #pragma unroll
    for (int i = 0; i < 4; ++i) {
        int e = (wr * 64 + i * 16 + l16) * 32 + quad * 8;
        offA[i] = e ^ (((e >> 6) & 3) << 3);
    }
    #pragma unroll
    for (int j = 0; j < 4; ++j) {
        int e = (wc * 64 + j * 16 + l16) * 32 + quad * 8;
        offB[j] = e ^ (((e >> 6) & 3) << 3);
    }

    // Staging source decode: lane's linear LDS slot o holds logical elem
    // swz(o) (involution) -> per-lane global addr pre-swizzled; LDS linear.
    const int oA  = wave * 512 + lane * 8;
    const int eA  = oA ^ (((oA >> 6) & 3) << 3);
    const bf16* gA  = A  + (size_t)(rowBase + (eA >> 5)) * K + (eA & 31);
    const int oB0 = wave * 512 + lane * 8;
    const int eB0 = oB0 ^ (((oB0 >> 6) & 3) << 3);
    const bf16* gB0 = Bt + (size_t)(colBase + (eB0 >> 5)) * K + (eB0 & 31);
    const int oB1 = 4096 + wave * 512 + lane * 8;
    const int eB1 = oB1 ^ (((oB1 >> 6) & 3) << 3);
    const bf16* gB1 = Bt + (size_t)(colBase + ((eB1 - 4096) >> 5) + 128) * K + (eB1 & 31);

    f32x4 acc[4][4] = {};

    // prologue: slices 0,1,2 in flight (9 loads/wave), wait oldest -> vmcnt(6)
    #pragma unroll
    for (int s = 0; s < 3; ++s) {
        bf16* lb = Ls + s * 12288 + wave * 512;
        load_lds16(gA  + s * 32, lb);
        load_lds16(gB0 + s * 32, lb + 4096);
        load_lds16(gB1 + s * 32, lb + 8192);
    }
    asm volatile("s_waitcnt vmcnt(6)" ::: "memory");
    __builtin_amdgcn_s_barrier();
    asm volatile("" ::: "memory");

    for (int s = 0; s < 61; ++s)
        GEMM_PHASE(s, 6, true);
    GEMM_PHASE(61, 3, false);
    GEMM_PHASE(62, 0, false);
    GEMM_PHASE(63, -1, false);

    // epilogue: C row = quad*4+r, col = l16 within each 16x16 fragment
    #pragma unroll
    for (int i = 0; i < 4; ++i) {
        #pragma unroll
        for (int j = 0; j < 4; ++j) {
            #pragma unroll
            for (int r = 0; r < 4; ++r) {
                const int row = rowBase + wr * 64 + i * 16 + quad * 4 + r;
                const int col = colBase + wc * 64 + j * 16 + l16;
                const float v = acc[i][j][r];
                if (OUT_F32_BIAS) ((float*)Cptr)[(size_t)row * N + col] = v + bias[col];
                else              ((bf16*)Cptr)[(size_t)row * N + col] = (bf16)v;
            }
        }
    }
}

// ---------------------------------------------------------------------------
// Attention, round-11: DROP the Ks LDS tile — read K fragments directly from
// global (L2-hot). Mechanism (Common-mistake #7): the head's K stream (512KB)
// is shared by its 16 q-tile blocks, all on one XCD via the existing swizzle
// -> L2-resident. The Ks path (4 global + 4 ds_write_b128 + 16 ds_read_b128
// per wave-kt) was ~40% of the LDS-pipe issue floor in an LDS-issue-bound
// kernel; direct VMEM fragment loads (16 x global b128 per wave-kt, lane
// addr = (kt*64+mt*16+l16)*DIM + ks*32+quad*8, 16x64B lines per inst — same
// line count as a coalesced 1KB load) move that work to the idle VMEM pipe.
// Issue-order ledger: akg(kt) issued BEFORE va/vb(kt+1) -> S^T's implicit
// wait is vmcnt(4), leaving the V-prefetch in flight across the compute.
// Hazards: Ps is wave-private; Vt still double-barriered. LDS 52->36 KB.
// V/P paths, S^T math, PV, epilogue unchanged from round-8 (90.7 us).
// ---------------------------------------------------------------------------
__global__ __launch_bounds__(256, 2)
void attn_kernel(const bf16* __restrict__ q, bf16* __restrict__ y)
{
    __shared__ bf16 Vt[HDIM * VSTRIDE];   // 18432 B  [hd][kv]
    __shared__ bf16 Ps[128 * PSTRIDE];    // 18432 B  [q][kv]

    const int tid  = threadIdx.x;
    const int wave = tid >> 6;     // 0..3
    const int lane = tid & 63;
    const int quad = lane >> 4;
    const int l16  = lane & 15;

    // XCD swizzle: p -> (qt, h, b) with all qt of a (b,h) on one XCD.
    const int p   = blockIdx.x;
    const int xcd = p & 7;
    const int pos = p >> 3;
    const int g   = xcd * 4 + (pos & 3);   // (b,h) group 0..31
    const int qt  = pos >> 2;              // 0..15
    const int h   = g & 15;
    const int bb  = g >> 4;

    const bf16* qb = q + (size_t)bb * SEQ * DIM + (size_t)h * HDIM;

    // Q fragments -> registers (wave owns q rows [wave*32, wave*32+32)).
    const float qs = 0.12752820031096662f;   // (1/sqrt(128)) * log2(e)
    bf16x8 aq[2][4];
    #pragma unroll
    for (int nt = 0; nt < 2; ++nt) {
        #pragma unroll
        for (int ks = 0; ks < 4; ++ks) {
            const bf16* src = qb + (size_t)(qt * 128 + wave * 32 + nt * 16 + l16) * DIM + ks * 32 + quad * 8;
            bf16x8 v = *(const bf16x8*)src;
            bf16x8 o;
            #pragma unroll
            for (int e = 0; e < 8; ++e) o[e] = (bf16)((float)v[e] * qs);
            aq[nt][ks] = o;
        }
    }

    float lpart[2] = {0.f, 0.f};
    f32x4 yacc[2][8] = {};

    // V staging map (conflict-free transposed commit, unchanged)
    const int sp   = tid & 31;         // kv pair (Vt path)
    const int ss   = tid >> 5;         // hd slice of 16
    const bf16* srcV = qb + (size_t)(2 * sp) * DIM + ss * 16;

    // K fragment base (lane-specific; row advances by kt*64 + mt*16)
    const bf16* akb = qb + (size_t)l16 * DIM + quad * 8;

    // prologue: V(0) reg prefetch
    bf16x8 va[2], vb[2];
    va[0] = *(const bf16x8*)(srcV + 0);
    va[1] = *(const bf16x8*)(srcV + 8);
    vb[0] = *(const bf16x8*)(srcV + DIM + 0);
    vb[1] = *(const bf16x8*)(srcV + DIM + 8);

    for (int kt = 0; kt < SEQ / 64; ++kt) {
        // issue K-fragment loads for THIS tile (VMEM, L2-hot; no LDS).
        // Issued before va/vb(kt+1) so S^T's wait leaves the V-prefetch
        // in flight (in-order vmcnt FIFO).
        bf16x8 akg[4][4];
        #pragma unroll
        for (int mt = 0; mt < 4; ++mt)
            #pragma unroll
            for (int ks = 0; ks < 4; ++ks)
                akg[mt][ks] = *(const bf16x8*)(akb + (size_t)(kt * 64 + mt * 16) * DIM + ks * 32);

        __syncthreads();   // barrier1: prev iteration's Vt readers done

        // commit V(kt) to LDS (transposed, conflict-free)
        #pragma unroll
        for (int c = 0; c < 2; ++c)
            #pragma unroll
            for (int e = 0; e < 8; ++e)
                *(bf16x2*)&Vt[(ss * 16 + c * 8 + e) * VSTRIDE + 2 * sp] = (bf16x2){va[c][e], vb[c][e]};

        // prefetch V(kt+1) regs (stays in flight across the compute phase)
        if (kt + 1 < SEQ / 64) {
            const bf16* nV = srcV + (size_t)(kt + 1) * 64 * DIM;
            va[0] = *(const bf16x8*)(nV + 0);
            va[1] = *(const bf16x8*)(nV + 8);
            vb[0] = *(const bf16x8*)(nV + DIM + 0);
            vb[1] = *(const bf16x8*)(nV + DIM + 8);
        }
        __syncthreads();   // barrier2: V(kt) committed

        // S^T phase per 16-kv strip (mt): MFMA(A=K-frag from regs, B=aq).
        // C-layout of S^T: kv = mt*16 + quad*4 + r, q = wave*32 + nt*16 + l16.
        #pragma unroll
        for (int mt = 0; mt < 4; ++mt) {
            f32x4 s[2] = {};
            __builtin_amdgcn_s_setprio(1);
            #pragma unroll
            for (int ks = 0; ks < 4; ++ks)
                #pragma unroll
                for (int nt = 0; nt < 2; ++nt)
                    s[nt] = __builtin_amdgcn_mfma_f32_16x16x32_bf16(akg[mt][ks], aq[nt][ks], s[nt], 0, 0, 0);
            __builtin_amdgcn_s_setprio(0);
            #pragma unroll
            for (int nt = 0; nt < 2; ++nt) {
                float p0 = exp2_hw(s[nt][0]);
                float p1 = exp2_hw(s[nt][1]);
                float p2 = exp2_hw(s[nt][2]);
                float p3 = exp2_hw(s[nt][3]);
                lpart[nt] += (p0 + p1) + (p2 + p3);
                *(bf16x4*)&Ps[(wave * 32 + nt * 16 + l16) * PSTRIDE + mt * 16 + quad * 4] =
                    (bf16x4){(bf16)p0, (bf16)p1, (bf16)p2, (bf16)p3};
            }
        }

        // PV: Y += P @ V. A = own-wave P rows (in-wave LDS dep only), B = V^T.
        #pragma unroll
        for (int ks2 = 0; ks2 < 2; ++ks2) {
            bf16x8 ap[2];
            #pragma unroll
            for (int i = 0; i < 2; ++i)
                ap[i] = *(const bf16x8*)&Ps[(wave * 32 + i * 16 + l16) * PSTRIDE + ks2 * 32 + quad * 8];
            __builtin_amdgcn_s_setprio(1);
            #pragma unroll
            for (int n = 0; n < 8; ++n) {
                bf16x8 bv = *(const bf16x8*)&Vt[(n * 16 + l16) * VSTRIDE + ks2 * 32 + quad * 8];
                #pragma unroll
                for (int i = 0; i < 2; ++i)
                    yacc[i][n] = __builtin_amdgcn_mfma_f32_16x16x32_bf16(ap[i], bv, yacc[i][n], 0, 0, 0);
            }
            __builtin_amdgcn_s_setprio(0);
        }
    }

    // denominators: reduce across the 4 quad-lanes sharing each q.
    float lfull[2];
    #pragma unroll
    for (int nt = 0; nt < 2; ++nt) {
        float l = lpart[nt];
        l += __shfl_xor(l, 16);
        l += __shfl_xor(l, 32);
        lfull[nt] = l;
    }

    // epilogue: yacc C-layout row = wave*32 + i*16 + quad*4 + r (q),
    // col = n*16 + l16 (hd).
    bf16* yb = y + (size_t)bb * SEQ * DIM + (size_t)(qt * 128) * DIM + (size_t)h * HDIM;
    #pragma unroll
    for (int i = 0; i < 2; ++i) {
        #pragma unroll
        for (int r = 0; r < 4; ++r) {
            const float lv  = __shfl(lfull[i], (lane & 48) | (quad * 4 + r));
            const float inv = 1.f / lv;
            const int row = wave * 32 + i * 16 + quad * 4 + r;
            #pragma unroll
            for (int n = 0; n < 8; ++n)
                yb[(size_t)row * DIM + n * 16 + l16] = (bf16)(yacc[i][n][r] * inv);
        }
    }
}

// ---------------------------------------------------------------------------
// Workspace layout (unchanged):
//   ws[0 .. N)        qws  (gemm1 out, attn in)           N = 16.78 MB
//   ws[N .. 2N)       yws  (attn out, gemm2 in); first 8.39 MB doubles as Wtq
//   ws[2N .. 2N+W)    Wto                                  W = 8.39 MB
//   d_out[0 .. N)     xb   (bf16 scratch; dead before gemm2 overwrites d_out)
// ---------------------------------------------------------------------------
extern "C" void kernel_launch(void* const* d_in, const int* in_sizes, int n_in,
                              void* d_out, int out_size, void* d_ws, size_t ws_size,
                              hipStream_t stream)
{
    const float* x  = (const float*)d_in[0];
    const float* Wq = (const float*)d_in[1];
    const float* Wo = (const float*)d_in[2];
    const float* bo = (const float*)d_in[3];
    float* out = (float*)d_out;

    const size_t NELEM = (size_t)BATCH * SEQ * DIM;
    bf16* qws = (bf16*)d_ws;
    bf16* yws = qws + NELEM;
    bf16* Wtq = yws;                 // aliased: safe, gemm1 precedes attn
    bf16* Wto = qws + 2 * NELEM;
    bf16* xb  = (bf16*)d_out;        // scratch inside d_out, dead by gemm2

    const int M = BATCH * SEQ;       // 4096

    prep_kernel<<<6144, 256, 0, stream>>>(x, xb, Wq, Wtq, Wo, Wto);
    gemm_bt8<false><<<256, 512, 0, stream>>>(xb, Wtq, nullptr, qws, M, DIM, DIM);
    attn_kernel<<<512, 256, 0, stream>>>(qws, yws);
    gemm_bt8<true><<<256, 512, 0, stream>>>(yws, Wto, bo, out, M, DIM, DIM);
}

// Round 12
// 255.992 us; speedup vs baseline: 1.2979x; 1.2979x over previous
//
#include <hip/hip_runtime.h>
#include <hip/hip_bf16.h>

#define BATCH 2
#define SEQ   2048
#define DIM   2048
#define NHEAD 16
#define HDIM  128

// LDS strides (elements) for attn V/P tiles. Multiples of 8 (16B alignment).
#define VSTRIDE 72
#define PSTRIDE 72

typedef __bf16 bf16;
typedef __attribute__((ext_vector_type(2))) __bf16 bf16x2;
typedef __attribute__((ext_vector_type(4))) __bf16 bf16x4;
typedef __attribute__((ext_vector_type(8))) __bf16 bf16x8;
typedef __attribute__((ext_vector_type(4))) float f32x4;

__device__ __forceinline__ void load_lds16(const bf16* g, bf16* l) {
    __builtin_amdgcn_global_load_lds((const __attribute__((address_space(1))) void*)g,
                                     (__attribute__((address_space(3))) void*)l, 16, 0, 0);
}

// v_exp_f32: D = 2^S0 (hardware transcendental)
__device__ __forceinline__ float exp2_hw(float x) { return __builtin_amdgcn_exp2f(x); }

// ---------------------------------------------------------------------------
// Fused prep (single dispatch, tasks run concurrently):
//   blocks [0, 4096):        cvt x fp32 -> xb bf16 (8 elems/thread)
//   blocks [4096, 5120):     transpose Wq -> Wtq (64x64 tiles)
//   blocks [5120, 6144):     transpose Wo -> Wto
// ---------------------------------------------------------------------------
__global__ __launch_bounds__(256)
void prep_kernel(const float* __restrict__ x, bf16* __restrict__ xb,
                 const float* __restrict__ Wq, bf16* __restrict__ Wtq,
                 const float* __restrict__ Wo, bf16* __restrict__ Wto)
{
    __shared__ bf16 T[64 * 72];
    const int bid = blockIdx.x;
    if (bid < 4096) {
        const size_t i = ((size_t)bid * 256 + threadIdx.x) * 8;
        const float4 f0 = *(const float4*)(x + i);
        const float4 f1 = *(const float4*)(x + i + 4);
        *(bf16x8*)(xb + i) = (bf16x8){(bf16)f0.x, (bf16)f0.y, (bf16)f0.z, (bf16)f0.w,
                                      (bf16)f1.x, (bf16)f1.y, (bf16)f1.z, (bf16)f1.w};
        return;
    }
    int t = bid - 4096;
    const float* W  = (t < 1024) ? Wq : Wo;
    bf16*        Wt = (t < 1024) ? Wtq : Wto;
    t &= 1023;
    const int kb = (t >> 5) * 64, nb = (t & 31) * 64;

    const int a = threadIdx.x & 31;     // k-pair index
    const int g = threadIdx.x >> 5;     // n-slice 0..7
    {
        const float* s0 = W + (size_t)(kb + 2 * a) * DIM + nb + g * 8;
        const float4 r0a = *(const float4*)(s0);
        const float4 r0b = *(const float4*)(s0 + 4);
        const float4 r1a = *(const float4*)(s0 + DIM);
        const float4 r1b = *(const float4*)(s0 + DIM + 4);
        float v0[8] = {r0a.x, r0a.y, r0a.z, r0a.w, r0b.x, r0b.y, r0b.z, r0b.w};
        float v1[8] = {r1a.x, r1a.y, r1a.z, r1a.w, r1b.x, r1b.y, r1b.z, r1b.w};
        #pragma unroll
        for (int i = 0; i < 8; ++i)
            *(bf16x2*)&T[(g * 8 + i) * 72 + 2 * a] = (bf16x2){(bf16)v0[i], (bf16)v1[i]};
    }
    __syncthreads();

    const int r  = threadIdx.x >> 2;          // output n row 0..63
    const int k0 = (threadIdx.x & 3) * 16;    // k chunk
    bf16x8 o0 = *(const bf16x8*)&T[r * 72 + k0];
    bf16x8 o1 = *(const bf16x8*)&T[r * 72 + k0 + 8];
    *(bf16x8*)(Wt + (size_t)(nb + r) * DIM + kb + k0)     = o0;
    *(bf16x8*)(Wt + (size_t)(nb + r) * DIM + kb + k0 + 8) = o1;
}

// ---------------------------------------------------------------------------
// GEMM — round-3 gemm_bt8 verbatim (best measured: ~73 us/gemm):
//   C[M,N] = A[M,K] @ Bt[N,K]^T, bf16 in. BM=128, BN=256, 8 waves 2Mx4N,
//   K in 64 slices of 32, 4-slot LDS ring (96 KiB), 256 blocks = 256 CUs.
// ---------------------------------------------------------------------------
#define GEMM_PHASE(S, VM, DO_STAGE)                                            \
    {                                                                          \
        const bf16* Aq = Ls + ((S) & 3) * 12288;                               \
        const bf16* Bq = Aq + 4096;                                            \
        bf16x8 a[4], b[4];                                                     \
        _Pragma("unroll")                                                      \
        for (int i = 0; i < 4; ++i) a[i] = *(const bf16x8*)(Aq + offA[i]);     \
        _Pragma("unroll")                                                      \
        for (int j = 0; j < 4; ++j) b[j] = *(const bf16x8*)(Bq + offB[j]);     \
        if (DO_STAGE) {                                                        \
            bf16* lb = Ls + (((S) + 3) & 3) * 12288 + wave * 512;              \
            const int ko = ((S) + 3) * 32;                                     \
            load_lds16(gA + ko, lb);                                           \
            load_lds16(gB0 + ko, lb + 4096);                                   \
            load_lds16(gB1 + ko, lb + 8192);                                   \
        }                                                                      \
        __builtin_amdgcn_s_barrier();                                          \
        __builtin_amdgcn_s_setprio(1);                                         \
        _Pragma("unroll")                                                      \
        for (int i = 0; i < 4; ++i) {                                          \
            _Pragma("unroll")                                                  \
            for (int j = 0; j < 4; ++j)                                        \
                acc[i][j] = __builtin_amdgcn_mfma_f32_16x16x32_bf16(a[i], b[j], acc[i][j], 0, 0, 0); \
        }                                                                      \
        __builtin_amdgcn_s_setprio(0);                                         \
        if ((VM) == 6)      asm volatile("s_waitcnt vmcnt(6)" ::: "memory");   \
        else if ((VM) == 3) asm volatile("s_waitcnt vmcnt(3)" ::: "memory");   \
        else if ((VM) == 0) asm volatile("s_waitcnt vmcnt(0)" ::: "memory");   \
        if ((VM) >= 0) {                                                       \
            __builtin_amdgcn_s_barrier();                                      \
            asm volatile("" ::: "memory");                                     \
        }                                                                      \
    }

template<bool OUT_F32_BIAS>
__global__ __launch_bounds__(512, 2)
void gemm_bt8(const bf16* __restrict__ A, const bf16* __restrict__ Bt,
              const float* __restrict__ bias, void* __restrict__ Cptr,
              int M, int N, int K)
{
    __shared__ bf16 Ls[4 * 12288];   // 96 KiB ring: slot = A[128][32] + B[256][32]

    const int tid  = threadIdx.x;
    const int wave = tid >> 6;        // 0..7
    const int lane = tid & 63;
    const int quad = lane >> 4;
    const int l16  = lane & 15;
    const int wr   = wave >> 2;       // 0..1: 64-row block
    const int wc   = wave & 3;        // 0..3: 64-col block

    // XCD swizzle (bijective: 256 blocks, 256%8==0).
    const int cpx = gridDim.x >> 3;
    const int logical = (blockIdx.x & 7) * cpx + (blockIdx.x >> 3);
    const int rowBase = (logical >> 3) * 128;   // NT = N/256 = 8
    const int colBase = (logical & 7) * 256;

    // s-invariant swizzled ds_read element offsets (region-relative)
    int offA[4], offB[4];
    #pragma unroll
    for (int i = 0; i < 4; ++i) {
        int e = (wr * 64 + i * 16 + l16) * 32 + quad * 8;
        offA[i] = e ^ (((e >> 6) & 3) << 3);
    }
    #pragma unroll
    for (int j = 0; j < 4; ++j) {
        int e = (wc * 64 + j * 16 + l16) * 32 + quad * 8;
        offB[j] = e ^ (((e >> 6) & 3) << 3);
    }

    // Staging source decode: lane's linear LDS slot o holds logical elem
    // swz(o) (involution) -> per-lane global addr pre-swizzled; LDS linear.
    const int oA  = wave * 512 + lane * 8;
    const int eA  = oA ^ (((oA >> 6) & 3) << 3);
    const bf16* gA  = A  + (size_t)(rowBase + (eA >> 5)) * K + (eA & 31);
    const int oB0 = wave * 512 + lane * 8;
    const int eB0 = oB0 ^ (((oB0 >> 6) & 3) << 3);
    const bf16* gB0 = Bt + (size_t)(colBase + (eB0 >> 5)) * K + (eB0 & 31);
    const int oB1 = 4096 + wave * 512 + lane * 8;
    const int eB1 = oB1 ^ (((oB1 >> 6) & 3) << 3);
    const bf16* gB1 = Bt + (size_t)(colBase + ((eB1 - 4096) >> 5) + 128) * K + (eB1 & 31);

    f32x4 acc[4][4] = {};

    // prologue: slices 0,1,2 in flight (9 loads/wave), wait oldest -> vmcnt(6)
    #pragma unroll
    for (int s = 0; s < 3; ++s) {
        bf16* lb = Ls + s * 12288 + wave * 512;
        load_lds16(gA  + s * 32, lb);
        load_lds16(gB0 + s * 32, lb + 4096);
        load_lds16(gB1 + s * 32, lb + 8192);
    }
    asm volatile("s_waitcnt vmcnt(6)" ::: "memory");
    __builtin_amdgcn_s_barrier();
    asm volatile("" ::: "memory");

    for (int s = 0; s < 61; ++s)
        GEMM_PHASE(s, 6, true);
    GEMM_PHASE(61, 3, false);
    GEMM_PHASE(62, 0, false);
    GEMM_PHASE(63, -1, false);

    // epilogue: C row = quad*4+r, col = l16 within each 16x16 fragment
    #pragma unroll
    for (int i = 0; i < 4; ++i) {
        #pragma unroll
        for (int j = 0; j < 4; ++j) {
            #pragma unroll
            for (int r = 0; r < 4; ++r) {
                const int row = rowBase + wr * 64 + i * 16 + quad * 4 + r;
                const int col = colBase + wc * 64 + j * 16 + l16;
                const float v = acc[i][j][r];
                if (OUT_F32_BIAS) ((float*)Cptr)[(size_t)row * N + col] = v + bias[col];
                else              ((bf16*)Cptr)[(size_t)row * N + col] = (bf16)v;
            }
        }
    }
}

// ---------------------------------------------------------------------------
// Attention, round-12: 8-wave q-tile-256 + single-barrier double-buffer.
// K path REVERTED to LDS staging (round-11's direct-L2 read quadrupled L2
// traffic: 90->160 us). Two structural changes vs round-8 (90.7 us):
//  (1) q-tile 256, 8 waves (512 thr), grid 2*16*8 = 256 = 1 block/CU:
//      K/V tile staged ONCE per CU per kt (was twice) -> staging writes and
//      global K/V fetch per CU both halve; per-wave compute identical
//      (each wave owns 32 q-rows).
//  (2) Ks+Vt double-buffered, ONE barrier per kt (was 2):
//      iter kt = {barrier; commit regs(kt+1)->buf[(kt+1)&1];
//                 load regs(kt+2); compute from buf[kt&1]}.
//      Safety: readers of buf[(kt+1)&1] (= compute(kt-1)) drained their
//      ds_reads before entering barrier(kt); commit(kt) precedes every
//      wave's barrier(kt) entry (syncthreads waits lgkmcnt) -> no race.
//      Ps is wave-private (write+read same wave, same phase): no barrier.
// LDS: Ks 2x16KB + Vt 2x18KB + Ps(256 rows) 36KB = 104 KB, 1 block/CU.
// Per-thread staging (512 thr): K = 2 bf16x8 (kr=tid>>3, koff=(tid&7)*16);
// V = 2 bf16x8, rows 2sp/2sp+1, 8-hd slice (sp=tid&31, ss8=tid>>5).
// Ks keeps the round-8 linear[64][128]+row-XOR layout (measured-neutral).
// ---------------------------------------------------------------------------
__global__ __launch_bounds__(512, 2)
void attn_kernel(const bf16* __restrict__ q, bf16* __restrict__ y)
{
    __shared__ bf16 Ks[2][64 * 128];       // 32768 B  [buf][kv][hd] linear+XOR
    __shared__ bf16 Vt[2][HDIM * VSTRIDE]; // 36864 B  [buf][hd][kv]
    __shared__ bf16 Ps[256 * PSTRIDE];     // 36864 B  [q][kv]

    const int tid  = threadIdx.x;
    const int wave = tid >> 6;     // 0..7
    const int lane = tid & 63;
    const int quad = lane >> 4;
    const int l16  = lane & 15;

    // XCD swizzle: p -> (qt, h, b) with all qt of a (b,h) on one XCD.
    const int p   = blockIdx.x;    // grid 256
    const int xcd = p & 7;
    const int pos = p >> 3;                // 0..31
    const int g   = xcd * 4 + (pos & 3);   // (b,h) group 0..31
    const int qt  = pos >> 2;              // 0..7 (q-tiles of 256)
    const int h   = g & 15;
    const int bb  = g >> 4;

    const bf16* qb = q + (size_t)bb * SEQ * DIM + (size_t)h * HDIM;

    // Q fragments -> registers (wave owns q rows [wave*32, wave*32+32) of the
    // 256-row q-tile).
    const float qs = 0.12752820031096662f;   // (1/sqrt(128)) * log2(e)
    bf16x8 aq[2][4];
    #pragma unroll
    for (int nt = 0; nt < 2; ++nt) {
        #pragma unroll
        for (int ks = 0; ks < 4; ++ks) {
            const bf16* src = qb + (size_t)(qt * 256 + wave * 32 + nt * 16 + l16) * DIM + ks * 32 + quad * 8;
            bf16x8 v = *(const bf16x8*)src;
            bf16x8 o;
            #pragma unroll
            for (int e = 0; e < 8; ++e) o[e] = (bf16)((float)v[e] * qs);
            aq[nt][ks] = o;
        }
    }

    float lpart[2] = {0.f, 0.f};
    f32x4 yacc[2][8] = {};

    // staging index maps (512 threads)
    const int kr   = tid >> 3;             // kv row 0..63 (Ks path)
    const int koff = (tid & 7) * 16;       // hd col chunk
    const int sp   = tid & 31;             // kv pair (Vt path)
    const int ss8  = tid >> 5;             // hd slice of 8, 0..15

    const bf16* srcK = qb + (size_t)kr * DIM + koff;
    const bf16* srcV = qb + (size_t)(2 * sp) * DIM + ss8 * 8;

    // commit helper targets
    bf16x8 kreg[2], va, vb;

    // prologue: load tile 0, commit to buf 0, load tile 1
    kreg[0] = *(const bf16x8*)(srcK);
    kreg[1] = *(const bf16x8*)(srcK + 8);
    va = *(const bf16x8*)(srcV);
    vb = *(const bf16x8*)(srcV + DIM);
    #pragma unroll
    for (int c = 0; c < 2; ++c)
        *(bf16x8*)&Ks[0][kr * 128 + ((koff + c * 8) ^ ((kr & 7) << 3))] = kreg[c];
    #pragma unroll
    for (int e = 0; e < 8; ++e)
        *(bf16x2*)&Vt[0][(ss8 * 8 + e) * VSTRIDE + 2 * sp] = (bf16x2){va[e], vb[e]};
    {
        const bf16* nK = srcK + (size_t)64 * DIM;
        const bf16* nV = srcV + (size_t)64 * DIM;
        kreg[0] = *(const bf16x8*)(nK);
        kreg[1] = *(const bf16x8*)(nK + 8);
        va = *(const bf16x8*)(nV);
        vb = *(const bf16x8*)(nV + DIM);
    }

    for (int kt = 0; kt < SEQ / 64; ++kt) {
        __syncthreads();   // buf[kt&1] fully committed; buf[(kt+1)&1] readers done

        // commit tile kt+1 into the other buffer (no conflict with readers
        // of buf[kt&1])
        if (kt + 1 < SEQ / 64) {
            const int nb = (kt + 1) & 1;
            #pragma unroll
            for (int c = 0; c < 2; ++c)
                *(bf16x8*)&Ks[nb][kr * 128 + ((koff + c * 8) ^ ((kr & 7) << 3))] = kreg[c];
            #pragma unroll
            for (int e = 0; e < 8; ++e)
                *(bf16x2*)&Vt[nb][(ss8 * 8 + e) * VSTRIDE + 2 * sp] = (bf16x2){va[e], vb[e]};
        }
        // prefetch tile kt+2 into registers (in flight across compute)
        if (kt + 2 < SEQ / 64) {
            const bf16* nK = srcK + (size_t)(kt + 2) * 64 * DIM;
            const bf16* nV = srcV + (size_t)(kt + 2) * 64 * DIM;
            kreg[0] = *(const bf16x8*)(nK);
            kreg[1] = *(const bf16x8*)(nK + 8);
            va = *(const bf16x8*)(nV);
            vb = *(const bf16x8*)(nV + DIM);
        }

        const bf16* Kb = Ks[kt & 1];
        const bf16* Vb = Vt[kt & 1];

        // S^T phase per 16-kv strip (mt): MFMA(A=Ks-frag, B=aq).
        // C-layout of S^T: kv = mt*16 + quad*4 + r, q = wave*32 + nt*16 + l16.
        #pragma unroll
        for (int mt = 0; mt < 4; ++mt) {
            bf16x8 ak[4];
            #pragma unroll
            for (int ks = 0; ks < 4; ++ks)
                ak[ks] = *(const bf16x8*)&Kb[(mt * 16 + l16) * 128 + ((ks * 32 + quad * 8) ^ ((l16 & 7) << 3))];
            f32x4 s[2] = {};
            __builtin_amdgcn_s_setprio(1);
            #pragma unroll
            for (int ks = 0; ks < 4; ++ks)
                #pragma unroll
                for (int nt = 0; nt < 2; ++nt)
                    s[nt] = __builtin_amdgcn_mfma_f32_16x16x32_bf16(ak[ks], aq[nt][ks], s[nt], 0, 0, 0);
            __builtin_amdgcn_s_setprio(0);
            #pragma unroll
            for (int nt = 0; nt < 2; ++nt) {
                float p0 = exp2_hw(s[nt][0]);
                float p1 = exp2_hw(s[nt][1]);
                float p2 = exp2_hw(s[nt][2]);
                float p3 = exp2_hw(s[nt][3]);
                lpart[nt] += (p0 + p1) + (p2 + p3);
                *(bf16x4*)&Ps[(wave * 32 + nt * 16 + l16) * PSTRIDE + mt * 16 + quad * 4] =
                    (bf16x4){(bf16)p0, (bf16)p1, (bf16)p2, (bf16)p3};
            }
        }

        // PV: Y += P @ V. A = own-wave P rows (in-wave LDS dep only), B = V^T.
        #pragma unroll
        for (int ks2 = 0; ks2 < 2; ++ks2) {
            bf16x8 ap[2];
            #pragma unroll
            for (int i = 0; i < 2; ++i)
                ap[i] = *(const bf16x8*)&Ps[(wave * 32 + i * 16 + l16) * PSTRIDE + ks2 * 32 + quad * 8];
            __builtin_amdgcn_s_setprio(1);
            #pragma unroll
            for (int n = 0; n < 8; ++n) {
                bf16x8 bv = *(const bf16x8*)&Vb[(n * 16 + l16) * VSTRIDE + ks2 * 32 + quad * 8];
                #pragma unroll
                for (int i = 0; i < 2; ++i)
                    yacc[i][n] = __builtin_amdgcn_mfma_f32_16x16x32_bf16(ap[i], bv, yacc[i][n], 0, 0, 0);
            }
            __builtin_amdgcn_s_setprio(0);
        }
    }

    // denominators: reduce across the 4 quad-lanes sharing each q.
    float lfull[2];
    #pragma unroll
    for (int nt = 0; nt < 2; ++nt) {
        float l = lpart[nt];
        l += __shfl_xor(l, 16);
        l += __shfl_xor(l, 32);
        lfull[nt] = l;
    }

    // epilogue: yacc C-layout row = wave*32 + i*16 + quad*4 + r (q),
    // col = n*16 + l16 (hd).
    bf16* yb = y + (size_t)bb * SEQ * DIM + (size_t)(qt * 256) * DIM + (size_t)h * HDIM;
    #pragma unroll
    for (int i = 0; i < 2; ++i) {
        #pragma unroll
        for (int r = 0; r < 4; ++r) {
            const float lv  = __shfl(lfull[i], (lane & 48) | (quad * 4 + r));
            const float inv = 1.f / lv;
            const int row = wave * 32 + i * 16 + quad * 4 + r;
            #pragma unroll
            for (int n = 0; n < 8; ++n)
                yb[(size_t)row * DIM + n * 16 + l16] = (bf16)(yacc[i][n][r] * inv);
        }
    }
}

// ---------------------------------------------------------------------------
// Workspace layout (unchanged):
//   ws[0 .. N)        qws  (gemm1 out, attn in)           N = 16.78 MB
//   ws[N .. 2N)       yws  (attn out, gemm2 in); first 8.39 MB doubles as Wtq
//   ws[2N .. 2N+W)    Wto                                  W = 8.39 MB
//   d_out[0 .. N)     xb   (bf16 scratch; dead before gemm2 overwrites d_out)
// ---------------------------------------------------------------------------
extern "C" void kernel_launch(void* const* d_in, const int* in_sizes, int n_in,
                              void* d_out, int out_size, void* d_ws, size_t ws_size,
                              hipStream_t stream)
{
    const float* x  = (const float*)d_in[0];
    const float* Wq = (const float*)d_in[1];
    const float* Wo = (const float*)d_in[2];
    const float* bo = (const float*)d_in[3];
    float* out = (float*)d_out;

    const size_t NELEM = (size_t)BATCH * SEQ * DIM;
    bf16* qws = (bf16*)d_ws;
    bf16* yws = qws + NELEM;
    bf16* Wtq = yws;                 // aliased: safe, gemm1 precedes attn
    bf16* Wto = qws + 2 * NELEM;
    bf16* xb  = (bf16*)d_out;        // scratch inside d_out, dead by gemm2

    const int M = BATCH * SEQ;       // 4096

    prep_kernel<<<6144, 256, 0, stream>>>(x, xb, Wq, Wtq, Wo, Wto);
    gemm_bt8<false><<<256, 512, 0, stream>>>(xb, Wtq, nullptr, qws, M, DIM, DIM);
    attn_kernel<<<256, 512, 0, stream>>>(qws, yws);
    gemm_bt8<true><<<256, 512, 0, stream>>>(yws, Wto, bo, out, M, DIM, DIM);
}